// Round 4
// baseline (230.766 us; speedup 1.0000x reference)
//
#include <hip/hip_runtime.h>

// Problem constants (match reference file)
constexpr int B = 32768;
constexpr int D = 1024;
constexpr int S = 64;
constexpr int O = 4;

// ---------------------------------------------------------------------------
// R4: ONE kernel, no sort, no workspace, no global atomics.
//
// R3 post-mortem: dur_us was identical to baseline (204.0 vs 204.1) and the
// timed graph is dominated by ~155us of 512MiB harness poison fills; the
// custom portion (~50us) was split as sort kernels + launches (~12us) + a
// BW-bound main (~30us, ideal 21us).  The sort bought W-residency but paid
// for itself in launches and perm indirection.
//
// New shape: grid = 64 subjects x 32 chunks.  Block (s, c) scans
// sid[c*1024 .. +1024) (coalesced, 64x redundant chip-wide = 8MB total),
// ballot-compacts rows with sid==s into a per-wave LDS list, loads W[s]
// into 64 VGPRs ONCE (no boundary reloads ever), then streams the matched
// x rows through the proven coalesced FMA + 12-shuffle-reduce pipeline with
// a named-buffer double-buffered prefetch.  Rows ascend within each block ->
// near-sequential 64-way interleaved x streams.  Every row is processed by
// exactly one (s,c) block; deterministic; no inter-block communication.
// ---------------------------------------------------------------------------

constexpr int CHUNKS      = 32;             // chunks per subject
constexpr int CHUNK       = B / CHUNKS;     // 1024 rows per block
constexpr int SEG         = CHUNK / 4;      // 256 rows per wave
constexpr int MAIN_BLOCKS = S * CHUNKS;     // 2048 blocks

__global__ __launch_bounds__(256, 4) void main_kernel(
    const float* __restrict__ x,      // [B, D]
    const int*   __restrict__ sid,    // [B]
    const float* __restrict__ W,      // [S, D, O]
    const float* __restrict__ bias,   // [S, O]
    float*       __restrict__ out)    // [B, O]
{
    __shared__ int list[4][SEG];              // per-wave private match lists

    const int lane = threadIdx.x & 63;
    const int wave = threadIdx.x >> 6;
    const int s    = blockIdx.x >> 5;         // 32 consecutive blocks share s
    const int c    = blockIdx.x & 31;
    const int q    = lane >> 4;               // output index this lane stores

    // ---- 1. Scan my 256-row segment of sid, compact matches into LDS ----
    const int seg = c * CHUNK + wave * SEG;
    int cnt = 0;
    #pragma unroll
    for (int r = 0; r < 4; ++r) {
        const int i = seg + r * 64 + lane;                 // coalesced 256B
        const bool m = (sid[i] == s);
        const unsigned long long mask = __ballot(m);
        const int rank = __popcll(mask & ((1ull << lane) - 1ull));
        if (m) list[wave][cnt + rank] = i;
        cnt += __popcll(mask);                             // lane-uniform
    }

    // ---- 2. W[s] register-resident: wreg[4j+cc] = W row (256j+4*lane+cc) --
    float4 wreg[16];
    {
        const float4* Wp = (const float4*)(W + (size_t)s * (D * O));
        #pragma unroll
        for (int jj = 0; jj < 4; ++jj)
            #pragma unroll
            for (int cc = 0; cc < 4; ++cc)
                wreg[4 * jj + cc] = Wp[256 * jj + 4 * lane + cc];
    }
    const float bb = bias[(s << 2) + q];       // uniform per block, once

    if (cnt == 0) return;                      // wave-private; no barriers used

#define LOADX(XB, ROW)                                                         \
    {                                                                          \
        const float4* xr = (const float4*)(x + ((size_t)(ROW) << 10));         \
        _Pragma("unroll")                                                      \
        for (int j = 0; j < 4; ++j) XB[j] = xr[64 * j + lane];                 \
    }

#define COMPUTE(XC, ROW)                                                       \
    {                                                                          \
        float a0 = 0.f, a1 = 0.f, a2 = 0.f, a3 = 0.f;                          \
        _Pragma("unroll")                                                      \
        for (int j = 0; j < 4; ++j) {                                          \
            const float4 xv = XC[j];                                           \
            const float4 w0 = wreg[4 * j + 0];                                 \
            const float4 w1 = wreg[4 * j + 1];                                 \
            const float4 w2 = wreg[4 * j + 2];                                 \
            const float4 w3 = wreg[4 * j + 3];                                 \
            a0 += xv.x * w0.x; a1 += xv.x * w0.y;                              \
            a2 += xv.x * w0.z; a3 += xv.x * w0.w;                              \
            a0 += xv.y * w1.x; a1 += xv.y * w1.y;                              \
            a2 += xv.y * w1.z; a3 += xv.y * w1.w;                              \
            a0 += xv.z * w2.x; a1 += xv.z * w2.y;                              \
            a2 += xv.z * w2.z; a3 += xv.z * w2.w;                              \
            a0 += xv.w * w3.x; a1 += xv.w * w3.y;                              \
            a2 += xv.w * w3.z; a3 += xv.w * w3.w;                              \
        }                                                                      \
        _Pragma("unroll")                                                      \
        for (int m = 16; m <= 32; m <<= 1) {                                   \
            a0 += __shfl_xor(a0, m, 64);                                       \
            a1 += __shfl_xor(a1, m, 64);                                       \
            a2 += __shfl_xor(a2, m, 64);                                       \
            a3 += __shfl_xor(a3, m, 64);                                       \
        }                                                                      \
        float v = (q == 0) ? a0 : (q == 1) ? a1 : (q == 2) ? a2 : a3;          \
        _Pragma("unroll")                                                      \
        for (int m = 1; m <= 8; m <<= 1)                                       \
            v += __shfl_xor(v, m, 64);                                         \
        if ((lane & 15) == 0)                                                  \
            out[((size_t)(ROW) << 2) + q] = v + bb;                            \
    }

    // ---- 3. Stream matched rows, named-buffer double-buffered prefetch ----
    float4 xbA[4], xbB[4];
    int rowA = __builtin_amdgcn_readfirstlane(list[wave][0]);
    LOADX(xbA, rowA)

    int k = 0;
    #pragma unroll 1
    while (k + 2 <= cnt) {
        const int rowB = __builtin_amdgcn_readfirstlane(list[wave][k + 1]);
        LOADX(xbB, rowB)
        COMPUTE(xbA, rowA)
        if (k + 2 < cnt) {
            const int rowN = __builtin_amdgcn_readfirstlane(list[wave][k + 2]);
            LOADX(xbA, rowN)
            COMPUTE(xbB, rowB)
            rowA = rowN;
        } else {
            COMPUTE(xbB, rowB)
        }
        k += 2;
    }
    if (k < cnt)                      // odd tail: xbA holds list[k]
        COMPUTE(xbA, rowA)

#undef LOADX
#undef COMPUTE
}

extern "C" void kernel_launch(void* const* d_in, const int* in_sizes, int n_in,
                              void* d_out, int out_size, void* d_ws, size_t ws_size,
                              hipStream_t stream) {
    const float* x    = (const float*)d_in[0];   // [B, D]
    const int*   sid  = (const int*)d_in[1];     // [B]
    const float* W    = (const float*)d_in[2];   // [S, D, O]
    const float* bias = (const float*)d_in[3];   // [S, O]
    float* out = (float*)d_out;                  // [B, O]

    main_kernel<<<MAIN_BLOCKS, 256, 0, stream>>>(x, sid, W, bias, out);
}

// Round 5
// 200.538 us; speedup vs baseline: 1.1507x; 1.1507x over previous
//
#include <hip/hip_runtime.h>

// Problem constants (match reference file)
constexpr int B = 32768;
constexpr int D = 1024;
constexpr int S = 64;
constexpr int O = 4;

// ---------------------------------------------------------------------------
// R5: one kernel, ballot-compaction (proven R4), but W in LDS, TRANSPOSED.
//
// R4 post-mortem: VGPR_Count=64 while the design needed ~115 (wreg[16] alone
// is 64) -> full pipeline spill.  WRITE_SIZE 57MB (= xb spill/restore per
// row) vs 0.5MB real output; 1.8 TB/s, 93us.  __launch_bounds__(256,4) did
// NOT raise the compiler's 64-reg budget (matches the R0-era note).
//
// Fix: W[s] (16KB) lives in LDS as 4 output-planes Wt[o][d].  Lane l, block
// j reads plane o at float4-index o*256 + 64j + l: 16B lane stride = the
// canonical conflict-free ds_read_b128 pattern.  (The natural [d][o] layout
// would be 64B lane stride = heavy bank conflicts.)  Per row: 4 coalesced
// float4 x-loads + 16 conflict-free ds_read_b128 + 64 FMA + 12-shuffle
// reduce.  Register need ~56 -> fits the 64-reg budget with NO spill, and
// occupancy doubles to 8 waves/SIMD.  LDS = 16KB Wt + 4KB list = 20480B ->
// exactly 8 blocks/CU, whole 2048-block grid co-resident.
// ---------------------------------------------------------------------------

constexpr int CHUNKS      = 32;             // chunks per subject
constexpr int CHUNK       = B / CHUNKS;     // 1024 rows per block
constexpr int SEG         = CHUNK / 4;      // 256 rows per wave
constexpr int MAIN_BLOCKS = S * CHUNKS;     // 2048 blocks

__global__ __launch_bounds__(256) void main_kernel(
    const float* __restrict__ x,      // [B, D]
    const int*   __restrict__ sid,    // [B]
    const float* __restrict__ W,      // [S, D, O]
    const float* __restrict__ bias,   // [S, O]
    float*       __restrict__ out)    // [B, O]
{
    __shared__ float Wt[O * D];               // 16 KB: plane o at Wt[o*1024 + d]
    __shared__ int   list[4][SEG];            // 4 KB: per-wave match lists

    const int t    = threadIdx.x;
    const int lane = t & 63;
    const int wave = t >> 6;
    const int s    = blockIdx.x >> 5;         // 32 consecutive blocks share s
    const int c    = blockIdx.x & 31;
    const int q    = lane >> 4;               // output index this lane stores

    // ---- 1. Stage W[s]^T into LDS (coalesced float4 reads, conflict-free
    //         scalar writes: bank = d%32 = t%32, 2 lanes/bank = free). ----
    {
        const float4* Wp = (const float4*)(W + (size_t)s * (D * O));
        #pragma unroll
        for (int r = 0; r < 4; ++r) {
            const int d = r * 256 + t;
            const float4 w4 = Wp[d];          // W[s][d][0..3]
            Wt[0 * D + d] = w4.x;
            Wt[1 * D + d] = w4.y;
            Wt[2 * D + d] = w4.z;
            Wt[3 * D + d] = w4.w;
        }
    }

    // ---- 2. Scan my 256-row sid segment, ballot-compact matches (R4-proven,
    //         wave-private list, no barrier needed for it). ----
    const int seg = c * CHUNK + wave * SEG;
    int cnt = 0;
    #pragma unroll
    for (int r = 0; r < 4; ++r) {
        const int i = seg + r * 64 + lane;                 // coalesced 256B
        const bool m = (sid[i] == s);
        const unsigned long long mask = __ballot(m);
        const int rank = __popcll(mask & ((1ull << lane) - 1ull));
        if (m) list[wave][cnt + rank] = i;
        cnt += __popcll(mask);                             // lane-uniform
    }

    __syncthreads();                          // Wt visible to all waves
    if (cnt == 0) return;                     // no barriers after this point

    const float   bb  = bias[(s << 2) + q];
    const float4* Wt4 = (const float4*)Wt;    // plane o at float4 index o*256

    // ---- 3. Stream matched rows.  Next-row index is fetched one iteration
    //         ahead (LDS latency hides under FMAs); next-row x loads issue
    //         right after current xb is consumed (reduce overlaps them). ----
    int rowC = __builtin_amdgcn_readfirstlane(list[wave][0]);
    float4 xb[4];
    {
        const float4* xr = (const float4*)(x + ((size_t)rowC << 10));
        #pragma unroll
        for (int j = 0; j < 4; ++j) xb[j] = xr[64 * j + lane];
    }

    #pragma unroll 1
    for (int k = 0; k < cnt; ++k) {
        const bool more = (k + 1 < cnt);
        const int rowN = more
            ? __builtin_amdgcn_readfirstlane(list[wave][k + 1]) : rowC;

        float a0 = 0.f, a1 = 0.f, a2 = 0.f, a3 = 0.f;
        #pragma unroll
        for (int j = 0; j < 4; ++j) {
            const float4 xv = xb[j];
            const float4 w0 = Wt4[0 * 256 + 64 * j + lane];  // conflict-free
            const float4 w1 = Wt4[1 * 256 + 64 * j + lane];
            const float4 w2 = Wt4[2 * 256 + 64 * j + lane];
            const float4 w3 = Wt4[3 * 256 + 64 * j + lane];
            a0 += xv.x * w0.x; a1 += xv.x * w1.x;
            a2 += xv.x * w2.x; a3 += xv.x * w3.x;
            a0 += xv.y * w0.y; a1 += xv.y * w1.y;
            a2 += xv.y * w2.y; a3 += xv.y * w3.y;
            a0 += xv.z * w0.z; a1 += xv.z * w1.z;
            a2 += xv.z * w2.z; a3 += xv.z * w3.z;
            a0 += xv.w * w0.w; a1 += xv.w * w1.w;
            a2 += xv.w * w2.w; a3 += xv.w * w3.w;
        }

        if (more) {                            // prefetch next row's x
            const float4* xr = (const float4*)(x + ((size_t)rowN << 10));
            #pragma unroll
            for (int j = 0; j < 4; ++j) xb[j] = xr[64 * j + lane];
        }

        // 12-op reduce: xor{16,32} on 4 accs -> per-(lane%16) partials;
        // lane picks q = lane>>4; xor{1,2,4,8} sums the 16 residues.
        #pragma unroll
        for (int m = 16; m <= 32; m <<= 1) {
            a0 += __shfl_xor(a0, m, 64);
            a1 += __shfl_xor(a1, m, 64);
            a2 += __shfl_xor(a2, m, 64);
            a3 += __shfl_xor(a3, m, 64);
        }
        float v = (q == 0) ? a0 : (q == 1) ? a1 : (q == 2) ? a2 : a3;
        #pragma unroll
        for (int m = 1; m <= 8; m <<= 1)
            v += __shfl_xor(v, m, 64);

        if ((lane & 15) == 0)                 // lanes 0,16,32,48 -> o = 0..3
            out[((size_t)rowC << 2) + q] = v + bb;

        rowC = rowN;
    }
}

extern "C" void kernel_launch(void* const* d_in, const int* in_sizes, int n_in,
                              void* d_out, int out_size, void* d_ws, size_t ws_size,
                              hipStream_t stream) {
    const float* x    = (const float*)d_in[0];   // [B, D]
    const int*   sid  = (const int*)d_in[1];     // [B]
    const float* W    = (const float*)d_in[2];   // [S, D, O]
    const float* bias = (const float*)d_in[3];   // [S, O]
    float* out = (float*)d_out;                  // [B, O]

    main_kernel<<<MAIN_BLOCKS, 256, 0, stream>>>(x, sid, W, bias, out);
}